// Round 3
// baseline (1632.338 us; speedup 1.0000x reference)
//
#include <hip/hip_runtime.h>
#include <hip/hip_bf16.h>

#define NNODES 10000
#define TLEN 24
#define INDIM 16
#define HID 128
#define GDIM 512  // 4*HID (LSTM gates) == HEADS*HID (GAT)

typedef __hip_bfloat16 bf16;
typedef short v8s __attribute__((ext_vector_type(8)));
typedef float v4f __attribute__((ext_vector_type(4)));

__device__ inline float b2f(bf16 v){ return __bfloat162float(v); }
__device__ inline float u2f(unsigned u){ return __uint_as_float(u); }

__device__ inline void unpack8(uint4 v, float* f){
  f[0]=u2f(v.x<<16); f[1]=u2f(v.x&0xFFFF0000u);
  f[2]=u2f(v.y<<16); f[3]=u2f(v.y&0xFFFF0000u);
  f[4]=u2f(v.z<<16); f[5]=u2f(v.z&0xFFFF0000u);
  f[6]=u2f(v.w<<16); f[7]=u2f(v.w&0xFFFF0000u);
}

__device__ inline float sigm(float x){ return 1.f/(1.f+__expf(-x)); }

// ---------------------------------------------------------------------------
// Convert the 11 f32 weight matrices used as MFMA B-operands into one bf16
// region. Chunks 0..9 are 65536-element [512,128]/[128,512] mats; chunk 10
// is mow0 (16384). Total 671744 elements = 2624 blocks x 256.
// ---------------------------------------------------------------------------
__global__ __launch_bounds__(256) void conv_w_k(
    const float* s0, const float* s1, const float* s2, const float* s3,
    const float* s4, const float* s5, const float* s6, const float* s7,
    const float* s8, const float* s9, const float* s10, bf16* __restrict__ dst)
{
  int idx = blockIdx.x*256 + threadIdx.x;
  if (idx >= 671744) return;
  int c = idx >> 16;
  float v;
  if (c < 10){
    const float* srcs[10] = {s0,s1,s2,s3,s4,s5,s6,s7,s8,s9};
    v = srcs[c][idx & 0xFFFF];
  } else {
    v = s10[idx - 655360];   // 16384 entries
  }
  dst[idx] = __float2bfloat16(v);
}

// ---------------------------------------------------------------------------
// Generic bf16 GEMM: C[M,N] = act(A[M,K] @ B[N,K]^T + bias_f32[N]), bf16 out.
// Tile 128x128, BK=32, 256 threads = 4 waves. K multiple of 32.
// ---------------------------------------------------------------------------
template<int ACT>
__global__ __launch_bounds__(256) void gemm_bt(
    const bf16* __restrict__ A, const bf16* __restrict__ B,
    const float* __restrict__ bias, bf16* __restrict__ C,
    int M, int N, int K)
{
  __shared__ __align__(16) bf16 As[128*40];
  __shared__ __align__(16) bf16 Bs[128*40];
  const int tid = threadIdx.x;
  const int m0 = blockIdx.x*128, n0 = blockIdx.y*128;
  const int lane = tid & 63, wave = tid >> 6;
  const int r16 = lane & 15, quad = lane >> 4;

  v4f acc[2][8];
  #pragma unroll
  for (int a=0;a<2;a++)
    #pragma unroll
    for (int b=0;b<8;b++) acc[a][b] = (v4f)0.f;

  for (int k0=0; k0<K; k0+=32){
    #pragma unroll
    for (int i=0;i<2;i++){
      int li = tid + i*256;
      int row = li >> 2, q4 = li & 3;
      uint4 va = make_uint4(0,0,0,0);
      int gm = m0 + row;
      if (gm < M) va = *(const uint4*)(A + (size_t)gm*K + k0 + q4*8);
      *(uint4*)(As + row*40 + q4*8) = va;
      uint4 vb = make_uint4(0,0,0,0);
      int gn = n0 + row;
      if (gn < N) vb = *(const uint4*)(B + (size_t)gn*K + k0 + q4*8);
      *(uint4*)(Bs + row*40 + q4*8) = vb;
    }
    __syncthreads();
    v8s av[2], bv[8];
    #pragma unroll
    for (int mi=0;mi<2;mi++)
      av[mi] = *(const v8s*)(As + (wave*32 + mi*16 + r16)*40 + quad*8);
    #pragma unroll
    for (int ni=0;ni<8;ni++)
      bv[ni] = *(const v8s*)(Bs + (ni*16 + r16)*40 + quad*8);
    #pragma unroll
    for (int mi=0;mi<2;mi++)
      #pragma unroll
      for (int ni=0;ni<8;ni++)
        acc[mi][ni] = __builtin_amdgcn_mfma_f32_16x16x32_bf16(av[mi], bv[ni], acc[mi][ni], 0, 0, 0);
    __syncthreads();
  }

  #pragma unroll
  for (int mi=0;mi<2;mi++){
    #pragma unroll
    for (int r=0;r<4;r++){
      int row = m0 + wave*32 + mi*16 + quad*4 + r;
      if (row >= M) continue;
      #pragma unroll
      for (int ni=0;ni<8;ni++){
        int col = n0 + ni*16 + r16;
        float v = acc[mi][ni][r] + bias[col];
        if (ACT == 1) v = v > 0.f ? v : 0.f;
        C[(size_t)row*N + col] = __float2bfloat16(v);
      }
    }
  }
}

// ---------------------------------------------------------------------------
// Fused LSTM step. Grid (79, 4); block y (=cb) owns hidden cols
// [32cb,32cb+32) of all four gates (B staging gathers gate rows).
// ---------------------------------------------------------------------------
__global__ __launch_bounds__(256) void lstm_step(
    const bf16* __restrict__ X, const bf16* __restrict__ Hprev,
    const bf16* __restrict__ Wih, const bf16* __restrict__ Whh,
    const float* __restrict__ bih, const float* __restrict__ bhh,
    float* __restrict__ cst, bf16* __restrict__ Hout, int M)
{
  __shared__ __align__(16) bf16 As[128*40];
  __shared__ __align__(16) bf16 Bs[128*40];
  const int tid = threadIdx.x;
  const int m0 = blockIdx.x*128;
  const int cb = blockIdx.y;
  const int lane = tid & 63, wave = tid >> 6;
  const int r16 = lane & 15, quad = lane >> 4;

  v4f acc[2][8];
  #pragma unroll
  for (int a=0;a<2;a++)
    #pragma unroll
    for (int b=0;b<8;b++) acc[a][b] = (v4f)0.f;

  for (int ph=0; ph<2; ph++){
    const bf16* Ap = ph ? Hprev : X;
    const bf16* Wp = ph ? Whh : Wih;
    for (int k0=0; k0<128; k0+=32){
      #pragma unroll
      for (int i=0;i<2;i++){
        int li = tid + i*256;
        int row = li >> 2, q4 = li & 3;
        uint4 va = make_uint4(0,0,0,0);
        int gm = m0 + row;
        if (gm < M) va = *(const uint4*)(Ap + (size_t)gm*HID + k0 + q4*8);
        *(uint4*)(As + row*40 + q4*8) = va;
        int wr = ((row>>5)*HID) + cb*32 + (row & 31);  // gate row gather
        uint4 vb = *(const uint4*)(Wp + (size_t)wr*HID + k0 + q4*8);
        *(uint4*)(Bs + row*40 + q4*8) = vb;
      }
      __syncthreads();
      v8s av[2], bv[8];
      #pragma unroll
      for (int mi=0;mi<2;mi++)
        av[mi] = *(const v8s*)(As + (wave*32 + mi*16 + r16)*40 + quad*8);
      #pragma unroll
      for (int ni=0;ni<8;ni++)
        bv[ni] = *(const v8s*)(Bs + (ni*16 + r16)*40 + quad*8);
      #pragma unroll
      for (int mi=0;mi<2;mi++)
        #pragma unroll
        for (int ni=0;ni<8;ni++)
          acc[mi][ni] = __builtin_amdgcn_mfma_f32_16x16x32_bf16(av[mi], bv[ni], acc[mi][ni], 0, 0, 0);
      __syncthreads();
    }
  }

  #pragma unroll
  for (int mi=0;mi<2;mi++){
    #pragma unroll
    for (int r=0;r<4;r++){
      int row = m0 + wave*32 + mi*16 + quad*4 + r;
      if (row >= M) continue;
      #pragma unroll
      for (int half=0; half<2; half++){
        int hcol = cb*32 + half*16 + r16;
        float iv = acc[mi][0+half][r] + bih[      hcol] + bhh[      hcol];
        float fv = acc[mi][2+half][r] + bih[128 + hcol] + bhh[128 + hcol];
        float gv = acc[mi][4+half][r] + bih[256 + hcol] + bhh[256 + hcol];
        float ov = acc[mi][6+half][r] + bih[384 + hcol] + bhh[384 + hcol];
        float ig = sigm(iv), fg = sigm(fv);
        float gg = tanhf(gv), og = sigm(ov);
        size_t ci = (size_t)row*HID + hcol;
        float cn = fg*cst[ci] + ig*gg;
        cst[ci] = cn;
        Hout[ci] = __float2bfloat16(og*tanhf(cn));
      }
    }
  }
}

// ---------------------------------------------------------------------------
// Fold MLP-in: Wp = w1 @ w0 [128,16] fp32, bp = w1@b0 + b1 [128] fp32.
// ---------------------------------------------------------------------------
__global__ void prep_w_k(const float* __restrict__ w0, const float* __restrict__ b0,
                         const float* __restrict__ w1, const float* __restrict__ b1,
                         float* __restrict__ Wp, float* __restrict__ bp)
{
  int t = threadIdx.x;
  for (int idx = t; idx < HID*INDIM; idx += 256){
    int j = idx >> 4, d = idx & 15;
    float s = 0.f;
    for (int k=0;k<HID;k++) s += w1[j*HID+k] * w0[k*INDIM+d];
    Wp[idx] = s;
  }
  for (int j = t; j < HID; j += 256){
    float s = b1[j];
    for (int k=0;k<HID;k++) s += w1[j*HID+k] * b0[k];
    bp[j] = s;
  }
}

// X0[t*N+n][j] = relu(bp[j] + x[n,t,:]·Wp[j,:])   (f32 in, bf16 out)
__global__ __launch_bounds__(256) void mlp_in_k(
    const float* __restrict__ x, const float* __restrict__ Wp,
    const float* __restrict__ bp, bf16* __restrict__ X0)
{
  int g = blockIdx.x*256 + threadIdx.x;
  if (g >= TLEN*NNODES*HID) return;
  int j = g & 127;
  int m = g >> 7;
  int t = m / NNODES;
  int n = m - t*NNODES;
  const float* xr = x + ((size_t)n*TLEN + t)*INDIM;
  const float* wr = Wp + j*INDIM;
  float s = bp[j];
  #pragma unroll
  for (int kk=0;kk<4;kk++){
    float4 fx = *(const float4*)(xr + kk*4);
    s += fx.x*wr[kk*4+0] + fx.y*wr[kk*4+1] + fx.z*wr[kk*4+2] + fx.w*wr[kk*4+3];
  }
  s = s > 0.f ? s : 0.f;
  X0[(size_t)m*HID + j] = __float2bfloat16(s);
}

// ---------------------------------------------------------------------------
// CSR build
// ---------------------------------------------------------------------------
__global__ void deg_count_k(const int* __restrict__ dst, int* __restrict__ deg, int E){
  int e = blockIdx.x*256 + threadIdx.x;
  if (e < E){
    unsigned d = (unsigned)dst[e];
    if (d < (unsigned)NNODES) atomicAdd(&deg[d], 1);
  }
}

__global__ void scan_k(const int* __restrict__ deg, int* __restrict__ offs,
                       int* __restrict__ cursor, int n)
{
  __shared__ int part[256];
  __shared__ int base[256];
  int t = threadIdx.x;
  int lo = t*40, hi = lo+40;
  if (lo > n) lo = n;
  if (hi > n) hi = n;
  int s = 0;
  for (int i=lo;i<hi;i++) s += deg[i];
  part[t] = s;
  __syncthreads();
  if (t == 0){
    int run=0;
    for (int i=0;i<256;i++){ base[i]=run; run+=part[i]; }
    offs[n] = run;
  }
  __syncthreads();
  int run = base[t];
  for (int i=lo;i<hi;i++){ offs[i]=run; cursor[i]=run; run += deg[i]; }
}

__global__ void fill_k(const int* __restrict__ dst, int* __restrict__ cursor,
                       int* __restrict__ eids, int E){
  int e = blockIdx.x*256 + threadIdx.x;
  if (e < E){
    unsigned d = (unsigned)dst[e];
    if (d < (unsigned)NNODES){
      int p = atomicAdd(&cursor[d], 1);
      eids[p] = e;
    }
  }
}

// ---------------------------------------------------------------------------
// GATv2 edge scores. 1 wave / edge; 16 lanes per head. att is f32.
// ---------------------------------------------------------------------------
__global__ __launch_bounds__(256) void gat_score(
    const int* __restrict__ src, const int* __restrict__ dst,
    const bf16* __restrict__ xl, const bf16* __restrict__ xr,
    const float* __restrict__ att, float* __restrict__ score, int E)
{
  int e = blockIdx.x*4 + (threadIdx.x >> 6);
  if (e >= E) return;
  int lane = threadIdx.x & 63;
  unsigned s = (unsigned)src[e], d = (unsigned)dst[e];
  if (s >= NNODES) s = 0;
  if (d >= NNODES) d = 0;
  float fl[8], fr[8];
  unpack8(*(const uint4*)(xl + (size_t)s*GDIM + lane*8), fl);
  unpack8(*(const uint4*)(xr + (size_t)d*GDIM + lane*8), fr);
  float4 a0 = *(const float4*)(att + lane*8);
  float4 a1 = *(const float4*)(att + lane*8 + 4);
  float fa[8] = {a0.x,a0.y,a0.z,a0.w,a1.x,a1.y,a1.z,a1.w};
  float p = 0.f;
  #pragma unroll
  for (int q=0;q<8;q++){
    float v = fl[q] + fr[q];
    v = v > 0.f ? v : 0.2f*v;   // LeakyReLU(0.2)
    p += v*fa[q];
  }
  p += __shfl_xor(p, 1); p += __shfl_xor(p, 2);
  p += __shfl_xor(p, 4); p += __shfl_xor(p, 8);
  if ((lane & 15) == 0)
    score[(size_t)e*4 + (lane>>4)] = p;
}

// ---------------------------------------------------------------------------
// Segment softmax + aggregation, atomic-free. 1 wave / dst node.
// ---------------------------------------------------------------------------
__global__ __launch_bounds__(256) void gat_agg(
    const int* __restrict__ offs, const int* __restrict__ eids, const int* __restrict__ src,
    const float* __restrict__ score, const bf16* __restrict__ xl,
    const float* __restrict__ gbias, bf16* __restrict__ agg)
{
  int d = blockIdx.x*4 + (threadIdx.x >> 6);
  if (d >= NNODES) return;
  int lane = threadIdx.x & 63;
  int head = lane >> 4;
  int i0 = offs[d], i1 = offs[d+1];
  float mx = -3.4e38f;
  for (int i=i0; i<i1; i++){
    int e = eids[i];
    mx = fmaxf(mx, score[(size_t)e*4 + head]);
  }
  float den = 0.f;
  float acc[8] = {0,0,0,0,0,0,0,0};
  for (int i=i0; i<i1; i++){
    int e = eids[i];
    unsigned s = (unsigned)src[e];
    if (s >= NNODES) s = 0;
    float w = __expf(score[(size_t)e*4 + head] - mx);
    den += w;
    float fx[8];
    unpack8(*(const uint4*)(xl + (size_t)s*GDIM + lane*8), fx);
    #pragma unroll
    for (int q=0;q<8;q++) acc[q] += w*fx[q];
  }
  float r = 1.f/(den + 1e-16f);
  float4 b0 = *(const float4*)(gbias + lane*8);
  float4 b1 = *(const float4*)(gbias + lane*8 + 4);
  float fb[8] = {b0.x,b0.y,b0.z,b0.w,b1.x,b1.y,b1.z,b1.w};
  #pragma unroll
  for (int q=0;q<8;q++)
    agg[(size_t)d*GDIM + lane*8 + q] = __float2bfloat16(acc[q]*r + fb[q]);
}

// ---------------------------------------------------------------------------
// Final linear (N=24): f32 weights, f32 out.
// ---------------------------------------------------------------------------
__global__ __launch_bounds__(256) void mlp_final_k(
    const bf16* __restrict__ a, const float* __restrict__ w,
    const float* __restrict__ b, float* __restrict__ out)
{
  int g = blockIdx.x*256 + threadIdx.x;
  if (g >= NNODES*24) return;
  int j = g % 24;
  int row = g / 24;
  const bf16* ar = a + (size_t)row*HID;
  const float* wr = w + (size_t)j*HID;
  float s = b[j];
  for (int k=0;k<HID;k+=8){
    float fa[8];
    unpack8(*(const uint4*)(ar+k), fa);
    float4 w0 = *(const float4*)(wr + k);
    float4 w1 = *(const float4*)(wr + k + 4);
    s += fa[0]*w0.x + fa[1]*w0.y + fa[2]*w0.z + fa[3]*w0.w
       + fa[4]*w1.x + fa[5]*w1.y + fa[6]*w1.z + fa[7]*w1.w;
  }
  out[g] = s;
}

// ---------------------------------------------------------------------------

extern "C" void kernel_launch(void* const* d_in, const int* in_sizes, int n_in,
                              void* d_out, int out_size, void* d_ws, size_t ws_size,
                              hipStream_t stream)
{
  const float* x   = (const float*)d_in[0];
  const int*   ei  = (const int*)d_in[1];
  const int E = in_sizes[1] / 2;
  const int* srcp = ei;
  const int* dstp = ei + E;

  const float* miw0 = (const float*)d_in[2];
  const float* mib0 = (const float*)d_in[3];
  const float* miw1 = (const float*)d_in[4];
  const float* mib1 = (const float*)d_in[5];
  const float* wih0 = (const float*)d_in[6];
  const float* whh0 = (const float*)d_in[7];
  const float* bih0 = (const float*)d_in[8];
  const float* bhh0 = (const float*)d_in[9];
  const float* wih1 = (const float*)d_in[10];
  const float* whh1 = (const float*)d_in[11];
  const float* bih1 = (const float*)d_in[12];
  const float* bhh1 = (const float*)d_in[13];
  const float* g_wl[2]   = {(const float*)d_in[14], (const float*)d_in[22]};
  const float* g_bl[2]   = {(const float*)d_in[15], (const float*)d_in[23]};
  const float* g_wr[2]   = {(const float*)d_in[16], (const float*)d_in[24]};
  const float* g_br[2]   = {(const float*)d_in[17], (const float*)d_in[25]};
  const float* g_att[2]  = {(const float*)d_in[18], (const float*)d_in[26]};
  const float* g_bias[2] = {(const float*)d_in[19], (const float*)d_in[27]};
  const float* g_pw[2]   = {(const float*)d_in[20], (const float*)d_in[28]};
  const float* g_pb[2]   = {(const float*)d_in[21], (const float*)d_in[29]};
  const float* mow0 = (const float*)d_in[30];
  const float* mob0 = (const float*)d_in[31];
  const float* mow1 = (const float*)d_in[32];
  const float* mob1 = (const float*)d_in[33];
  (void)n_in; (void)out_size; (void)ws_size;

  // ---- workspace layout (~87 MB, aliased regions) ----
  char* base = (char*)d_ws;
  size_t off = 0;
  auto carve = [&](size_t n)->char*{
    char* p = base + off;
    off = (off + n + 255) & ~(size_t)255;
    return p;
  };
  char*  X0r = carve((size_t)TLEN*NNODES*HID*2);            // 61,440,000
  bf16*  h2a = (bf16*)carve((size_t)NNODES*HID*2);
  bf16*  h2b = (bf16*)carve((size_t)NNODES*HID*2);
  float* Wp  = (float*)carve(HID*INDIM*4);
  float* bp  = (float*)carve(HID*4);
  bf16*  wbf = (bf16*)carve((size_t)671744*2);              // bf16 weights
  char*  Lr  = carve(17920000);

  // wbf sub-pointers (order must match conv_w_k chunk order)
  const bf16* wih0b = wbf + 0;
  const bf16* whh0b = wbf + 65536;
  const bf16* wih1b = wbf + 131072;
  const bf16* whh1b = wbf + 196608;
  const bf16* wl0b  = wbf + 262144;
  const bf16* wr0b  = wbf + 327680;
  const bf16* pw0b  = wbf + 393216;
  const bf16* wl1b  = wbf + 458752;
  const bf16* wr1b  = wbf + 524288;
  const bf16* pw1b  = wbf + 589824;
  const bf16* mow0b = wbf + 655360;
  const bf16* wlb[2] = {wl0b, wl1b};
  const bf16* wrb[2] = {wr0b, wr1b};
  const bf16* pwb[2] = {pw0b, pw1b};

  // X0 region aliases (X0 dead once LSTM finishes)
  bf16* X0 = (bf16*)X0r;
  bf16* xl = (bf16*)X0r;
  bf16* xr = (bf16*)(X0r + 10240000);
  bf16* z2 = (bf16*)(X0r + 20480000);
  bf16* z3 = (bf16*)(X0r + 23040000);
  bf16* o0 = (bf16*)(X0r + 25600000);

  // L region: LSTM-phase scratch, later aliased by GAT-phase scratch
  bf16*  zb  = (bf16*)Lr;
  float* cb1 = (float*)(Lr + 2560000);
  float* cb2 = (float*)(Lr + 7680000);
  bf16*  h1a = (bf16*)(Lr + 12800000);
  bf16*  h1b = (bf16*)(Lr + 15360000);
  float* score = (float*)Lr;                      // 2,560,000
  int*   offsb = (int*)(Lr + 2560000);
  int*   curs  = (int*)(Lr + 2600192);
  int*   eids  = (int*)(Lr + 2640384);
  int*   deg   = (int*)(Lr + 3280640);
  bf16*  agg   = (bf16*)(Lr + 3320832);           // 10,240,000

  // ---- weight conversion + MLP-in fold ----
  conv_w_k<<<2624, 256, 0, stream>>>(wih0, whh0, wih1, whh1,
                                     g_wl[0], g_wr[0], g_pw[0],
                                     g_wl[1], g_wr[1], g_pw[1], mow0, wbf);
  prep_w_k<<<1, 256, 0, stream>>>(miw0, mib0, miw1, mib1, Wp, bp);
  mlp_in_k<<<(TLEN*NNODES*HID)/256, 256, 0, stream>>>(x, Wp, bp, X0);

  // ---- LSTM: both layers interleaved per timestep ----
  hipMemsetAsync(zb, 0, (size_t)NNODES*HID*2, stream);
  hipMemsetAsync(cb1, 0, (size_t)NNODES*HID*4, stream);
  hipMemsetAsync(cb2, 0, (size_t)NNODES*HID*4, stream);
  const dim3 gStep(79, 4);
  for (int t=0; t<TLEN; t++){
    const bf16* Xt  = X0 + (size_t)t*NNODES*HID;
    const bf16* Hp1 = (t==0) ? zb : ((t & 1) ? h1a : h1b);
    bf16* Ho1 = (t & 1) ? h1b : h1a;
    lstm_step<<<gStep, 256, 0, stream>>>(Xt, Hp1, wih0b, whh0b, bih0, bhh0, cb1, Ho1, NNODES);
    const bf16* Hp2 = (t==0) ? zb : ((t & 1) ? h2a : h2b);
    bf16* Ho2 = (t & 1) ? h2b : h2a;
    lstm_step<<<gStep, 256, 0, stream>>>(Ho1, Hp2, wih1b, whh1b, bih1, bhh1, cb2, Ho2, NNODES);
  }
  const bf16* z = h2b;   // t=23 (odd) wrote h2b

  // ---- CSR build ----
  hipMemsetAsync(deg, 0, (size_t)NNODES*4, stream);
  deg_count_k<<<(E+255)/256, 256, 0, stream>>>(dstp, deg, E);
  scan_k<<<1, 256, 0, stream>>>(deg, offsb, curs, NNODES);
  fill_k<<<(E+255)/256, 256, 0, stream>>>(dstp, curs, eids, E);

  // ---- GAT layers ----
  const bf16* zin = z;
  bf16* zouts[2] = {z2, z3};
  for (int l=0; l<2; l++){
    gemm_bt<0><<<dim3(79,4), 256, 0, stream>>>(zin, wlb[l], g_bl[l], xl, NNODES, GDIM, HID);
    gemm_bt<0><<<dim3(79,4), 256, 0, stream>>>(zin, wrb[l], g_br[l], xr, NNODES, GDIM, HID);
    gat_score<<<(E+3)/4, 256, 0, stream>>>(srcp, dstp, xl, xr, g_att[l], score, E);
    gat_agg<<<(NNODES+3)/4, 256, 0, stream>>>(offsb, eids, srcp, score, xl, g_bias[l], agg);
    gemm_bt<1><<<dim3(79,1), 256, 0, stream>>>(agg, pwb[l], g_pb[l], zouts[l], NNODES, HID, GDIM);
    zin = zouts[l];
  }

  // ---- MLP out ----
  gemm_bt<1><<<dim3(79,1), 256, 0, stream>>>(z3, mow0b, mob0, o0, NNODES, HID, HID);
  mlp_final_k<<<(NNODES*24+255)/256, 256, 0, stream>>>(o0, mow1, mob1, (float*)d_out);
}